// Round 1
// baseline (1604.040 us; speedup 1.0000x reference)
//
#include <hip/hip_runtime.h>
#include <hip/hip_fp16.h>

#define NB 4096      // batch
#define NK 64        // neighbors
#define ND 128       // dim
#define NH 4         // heads
#define ESTR 130     // padded LDS row stride (floats) for e_n / staging tiles

__device__ __forceinline__ float seluf(float x) {
    return 1.0507009873554805f * (x > 0.f ? x : 1.6732632423543772f * (expf(x) - 1.f));
}
__device__ __forceinline__ float sigmoidf_(float x) {
    return 1.f / (1.f + expf(-x));
}

// ---------------------------------------------------------------- kernel 1
__global__ __launch_bounds__(256, 2)
void k_att(const int* __restrict__ nodes, const int* __restrict__ neighbors,
           const float* __restrict__ u2e,
           const float* __restrict__ att1_w, const float* __restrict__ att1_b,
           const float* __restrict__ att2_w, const float* __restrict__ att2_b,
           const float* __restrict__ att3_w, const float* __restrict__ att3_b,
           const float* __restrict__ lin1_w, const float* __restrict__ lin1_b,
           float* __restrict__ hist_out)
{
    __shared__ float e_sh[NK * ESTR];       // normalized neighbor embeds, f32
    __shared__ __half s1_sh[NK * ESTR];     // sc1 (att1 output), f16
    __shared__ float u_sh[ND], un_sh[ND], up_sh[ND], lw_sh[ND], hist_sh[ND];
    __shared__ float alpha_sh[NK], sc_sh[NK], att_sh[NK];
    __shared__ float red_sh[256];
    __shared__ float rnorm_sh;

    const int b = blockIdx.x;
    const int t = threadIdx.x;
    const int lane = t & 63;
    const int wave = t >> 6;

    // ---- gather neighbors + l2norm into LDS ----
    for (int k = wave; k < NK; k += 4) {
        int idx = neighbors[b * NK + k];
        float2 v = ((const float2*)(u2e + (size_t)idx * ND))[lane];
        float ss = v.x * v.x + v.y * v.y;
        #pragma unroll
        for (int m = 1; m < 64; m <<= 1) ss += __shfl_xor(ss, m, 64);
        float r = 1.0f / fmaxf(sqrtf(ss), 1e-12f);
        e_sh[k * ESTR + 2 * lane]     = v.x * r;
        e_sh[k * ESTR + 2 * lane + 1] = v.y * r;
    }
    if (t < ND) {
        u_sh[t] = u2e[(size_t)nodes[b] * ND + t];
        hist_sh[t] = 0.f;
    }
    __syncthreads();

    for (int h = 0; h < NH; ++h) {
        // ---- u_n = l2norm(u) ----
        if (wave == 0) {
            float a = u_sh[lane], c = u_sh[lane + 64];
            float ss = a * a + c * c;
            #pragma unroll
            for (int m = 1; m < 64; m <<= 1) ss += __shfl_xor(ss, m, 64);
            if (lane == 0) rnorm_sh = 1.0f / fmaxf(sqrtf(ss), 1e-12f);
        }
        __syncthreads();
        if (t < ND) {
            un_sh[t] = u_sh[t] * rnorm_sh;
            lw_sh[t] = lin1_w[h * ND + t];
        }
        __syncthreads();

        // ---- uproj partials (rank-1 half of att1) ----
        {
            int d = t & 127, half = t >> 7;
            const float* wb = att1_w + (size_t)h * 32768 + (size_t)(ND + half * 64) * ND + d;
            float p = 0.f;
            #pragma unroll 8
            for (int j = 0; j < 64; ++j)
                p += un_sh[half * 64 + j] * wb[j * ND];
            red_sh[t] = p;
        }
        // ---- alpha = sigmoid(e_n . lin1_w + b) + 1 ----
        {
            int k = t >> 2, qd = t & 3;
            const float* er = e_sh + k * ESTR + qd * 32;
            const float* lr = lw_sh + qd * 32;
            float ap = 0.f;
            #pragma unroll 8
            for (int jj = 0; jj < 32; ++jj) ap += er[jj] * lr[jj];
            ap += __shfl_xor(ap, 1, 64);
            ap += __shfl_xor(ap, 2, 64);
            if (qd == 0)
                alpha_sh[k] = sigmoidf_(ap + lin1_b[h]) + 1.0f;
        }
        __syncthreads();
        if (t < ND)
            up_sh[t] = red_sh[t] + red_sh[t + 128] + att1_b[h * ND + t];
        __syncthreads();

        // ---- att1: sc1[k][d] = selu(e_n[k] . W1a[:,d] + up[d]) ----
        {
            const int dg = t & 15, kg = t >> 4;
            const int d0 = dg * 8, k0 = kg * 4;
            float acc[4][8] = {};
            const float* W = att1_w + (size_t)h * 32768 + d0;
            for (int j = 0; j < ND; ++j) {
                float4 wa = *(const float4*)(W + (size_t)j * ND);
                float4 wb = *(const float4*)(W + (size_t)j * ND + 4);
                float w[8] = {wa.x, wa.y, wa.z, wa.w, wb.x, wb.y, wb.z, wb.w};
                #pragma unroll
                for (int i = 0; i < 4; ++i) {
                    float e = e_sh[(k0 + i) * ESTR + j];
                    #pragma unroll
                    for (int c = 0; c < 8; ++c) acc[i][c] += e * w[c];
                }
            }
            #pragma unroll
            for (int i = 0; i < 4; ++i)
                #pragma unroll
                for (int c = 0; c < 8; ++c) {
                    float v = seluf(acc[i][c] + up_sh[d0 + c]);
                    s1_sh[(k0 + i) * ESTR + d0 + c] = __float2half(v);
                }
        }
        __syncthreads();

        // ---- att2 (+bias, selu) then att3 dot -> sc[k] ----
        {
            const int cg = t & 7, kg = t >> 3;
            const int c0 = cg * 4, k0 = kg * 2;
            float acc[2][4] = {};
            const float* W2 = att2_w + h * 4096 + c0;
            for (int d = 0; d < ND; ++d) {
                float4 w = *(const float4*)(W2 + d * 32);
                float e0 = __half2float(s1_sh[k0 * ESTR + d]);
                float e1 = __half2float(s1_sh[(k0 + 1) * ESTR + d]);
                acc[0][0] += e0 * w.x; acc[0][1] += e0 * w.y;
                acc[0][2] += e0 * w.z; acc[0][3] += e0 * w.w;
                acc[1][0] += e1 * w.x; acc[1][1] += e1 * w.y;
                acc[1][2] += e1 * w.z; acc[1][3] += e1 * w.w;
            }
            float p0 = 0.f, p1 = 0.f;
            #pragma unroll
            for (int c = 0; c < 4; ++c) {
                float w3 = att3_w[h * 32 + c0 + c];
                float b2 = att2_b[h * 32 + c0 + c];
                p0 += seluf(acc[0][c] + b2) * w3;
                p1 += seluf(acc[1][c] + b2) * w3;
            }
            p0 += __shfl_xor(p0, 1, 64); p0 += __shfl_xor(p0, 2, 64); p0 += __shfl_xor(p0, 4, 64);
            p1 += __shfl_xor(p1, 1, 64); p1 += __shfl_xor(p1, 2, 64); p1 += __shfl_xor(p1, 4, 64);
            if (cg == 0) {
                float b3 = att3_b[h];
                sc_sh[k0]     = p0 + b3;
                sc_sh[k0 + 1] = p1 + b3;
            }
        }
        __syncthreads();

        // ---- entmax bisection (each wave computes full row; wave 0 writes) ----
        {
            float x   = sc_sh[lane];
            float am1 = alpha_sh[lane] - 1.0f;
            float q   = 1.0f / am1;
            float xs  = x * am1;
            float mx = xs;
            #pragma unroll
            for (int m = 1; m < 64; m <<= 1) mx = fmaxf(mx, __shfl_xor(mx, m, 64));
            float lo = mx - 1.0f, hi = mx;
            for (int it = 0; it < 50; ++it) {
                float mid = 0.5f * (lo + hi);
                float tt = xs - mid;
                float p = (tt > 0.f) ? exp2f(q * log2f(tt)) : 0.f;
                float s = p;
                #pragma unroll
                for (int m = 1; m < 64; m <<= 1) s += __shfl_xor(s, m, 64);
                if (s >= 1.0f) lo = mid; else hi = mid;
            }
            float mid = 0.5f * (lo + hi);
            float tt = xs - mid;
            float p = (tt > 0.f) ? exp2f(q * log2f(tt)) : 0.f;
            float s = p;
            #pragma unroll
            for (int m = 1; m < 64; m <<= 1) s += __shfl_xor(s, m, 64);
            if (wave == 0) att_sh[lane] = p / s;
        }
        __syncthreads();

        // ---- pool: u[d] = sum_k e_n[k][d] * att[k]; hist += u ----
        {
            int d = t & 127, half = t >> 7;
            const float* er = e_sh + (half * 32) * ESTR + d;
            float p = 0.f;
            #pragma unroll 8
            for (int k = 0; k < 32; ++k)
                p += er[k * ESTR] * att_sh[half * 32 + k];
            red_sh[t] = p;
        }
        __syncthreads();
        if (t < ND) {
            float un = red_sh[t] + red_sh[t + 128];
            u_sh[t] = un;
            hist_sh[t] += un;
        }
        __syncthreads();
    }
    if (t < ND) hist_out[(size_t)b * ND + t] = hist_sh[t] * 0.25f;
}

// ---------------------------------------------------------------- column stats
__global__ __launch_bounds__(256)
void k_colstats(const float* __restrict__ x,
                float* __restrict__ sums, float* __restrict__ sumsq)
{
    __shared__ float rs[256], rq[256];
    int t = threadIdx.x;
    int d = t & 127, rh = t >> 7;
    int row0 = blockIdx.x * 32;
    float s = 0.f, q = 0.f;
    #pragma unroll 4
    for (int i = 0; i < 16; ++i) {
        int r = row0 + rh * 16 + i;
        float v = x[(size_t)r * ND + d];
        s += v; q += v * v;
    }
    rs[t] = s; rq[t] = q;
    __syncthreads();
    if (t < ND) {
        atomicAdd(&sums[d],  rs[t] + rs[t + 128]);
        atomicAdd(&sumsq[d], rq[t] + rq[t + 128]);
    }
}

// ---------------------------------------------------------------- h1 = selu(bn(hist) @ in_w + in_b)
__global__ __launch_bounds__(256)
void k_mlp1(const float* __restrict__ hist,
            const float* __restrict__ sums, const float* __restrict__ sumsq,
            const float* __restrict__ bn_g, const float* __restrict__ bn_b,
            const float* __restrict__ in_w, const float* __restrict__ in_b,
            float* __restrict__ h1out)
{
    __shared__ float xh[32 * ESTR];
    int t = threadIdx.x;
    int row0 = blockIdx.x * 32;
    for (int i = t; i < 32 * ND; i += 256) {
        int r = i >> 7, d = i & 127;
        float m  = sums[d]  * (1.f / 4096.f);
        float vv = sumsq[d] * (1.f / 4096.f) - m * m;
        float sc = bn_g[d] * rsqrtf(vv + 1e-5f);
        float sh = bn_b[d] - m * sc;
        xh[r * ESTR + d] = hist[(size_t)(row0 + r) * ND + d] * sc + sh;
    }
    __syncthreads();
    int dg = t & 15, rg = t >> 4;
    int d0 = dg * 8, r0 = rg * 2;
    float acc[2][8] = {};
    for (int j = 0; j < ND; ++j) {
        const float* wr = in_w + (size_t)j * ND + d0;
        float4 wa = *(const float4*)wr, wb = *(const float4*)(wr + 4);
        float w[8] = {wa.x, wa.y, wa.z, wa.w, wb.x, wb.y, wb.z, wb.w};
        float e0 = xh[r0 * ESTR + j], e1 = xh[(r0 + 1) * ESTR + j];
        #pragma unroll
        for (int c = 0; c < 8; ++c) { acc[0][c] += e0 * w[c]; acc[1][c] += e1 * w[c]; }
    }
    #pragma unroll
    for (int i = 0; i < 2; ++i)
        #pragma unroll
        for (int c = 0; c < 8; ++c) {
            int d = d0 + c;
            h1out[(size_t)(row0 + r0 + i) * ND + d] = seluf(acc[i][c] + in_b[d]);
        }
}

// ---------------------------------------------------------------- final: neigh = bn1(h1)@out_w+b; gated combine
__global__ __launch_bounds__(256)
void k_final(const float* __restrict__ h1,
             const float* __restrict__ sums1, const float* __restrict__ sumsq1,
             const float* __restrict__ bn1_g, const float* __restrict__ bn1_b,
             const float* __restrict__ out_w, const float* __restrict__ out_b,
             const float* __restrict__ gate_w, const float* __restrict__ gate_b,
             const int* __restrict__ nodes, const float* __restrict__ u2e,
             float* __restrict__ out)
{
    __shared__ float xh[32 * ESTR];
    __shared__ float sf[32 * ESTR];
    __shared__ float ng[32 * ESTR];
    int t = threadIdx.x;
    int row0 = blockIdx.x * 32;
    for (int i = t; i < 32 * ND; i += 256) {
        int r = i >> 7, d = i & 127;
        float m  = sums1[d]  * (1.f / 4096.f);
        float vv = sumsq1[d] * (1.f / 4096.f) - m * m;
        float sc = bn1_g[d] * rsqrtf(vv + 1e-5f);
        float sh = bn1_b[d] - m * sc;
        xh[r * ESTR + d] = h1[(size_t)(row0 + r) * ND + d] * sc + sh;
        sf[r * ESTR + d] = u2e[(size_t)nodes[row0 + r] * ND + d];
    }
    __syncthreads();
    int dg = t & 15, rg = t >> 4;
    int d0 = dg * 8, r0 = rg * 2;
    {
        float acc[2][8] = {};
        for (int j = 0; j < ND; ++j) {
            const float* wr = out_w + (size_t)j * ND + d0;
            float4 wa = *(const float4*)wr, wb = *(const float4*)(wr + 4);
            float w[8] = {wa.x, wa.y, wa.z, wa.w, wb.x, wb.y, wb.z, wb.w};
            float e0 = xh[r0 * ESTR + j], e1 = xh[(r0 + 1) * ESTR + j];
            #pragma unroll
            for (int c = 0; c < 8; ++c) { acc[0][c] += e0 * w[c]; acc[1][c] += e1 * w[c]; }
        }
        #pragma unroll
        for (int i = 0; i < 2; ++i)
            #pragma unroll
            for (int c = 0; c < 8; ++c)
                ng[(r0 + i) * ESTR + d0 + c] = acc[i][c] + out_b[d0 + c];
    }
    __syncthreads();
    {
        float acc[2][8] = {};
        for (int j = 0; j < ND; ++j) {
            const float* g0 = gate_w + (size_t)j * ND + d0;
            const float* g1 = gate_w + (size_t)(ND + j) * ND + d0;
            const float* g2 = gate_w + (size_t)(2 * ND + j) * ND + d0;
            float4 a0 = *(const float4*)g0, b0 = *(const float4*)(g0 + 4);
            float4 a1 = *(const float4*)g1, b1 = *(const float4*)(g1 + 4);
            float4 a2 = *(const float4*)g2, b2 = *(const float4*)(g2 + 4);
            float w0[8] = {a0.x, a0.y, a0.z, a0.w, b0.x, b0.y, b0.z, b0.w};
            float w1[8] = {a1.x, a1.y, a1.z, a1.w, b1.x, b1.y, b1.z, b1.w};
            float w2[8] = {a2.x, a2.y, a2.z, a2.w, b2.x, b2.y, b2.z, b2.w};
            #pragma unroll
            for (int i = 0; i < 2; ++i) {
                float s = sf[(r0 + i) * ESTR + j];
                float n = ng[(r0 + i) * ESTR + j];
                float p = s * n;
                #pragma unroll
                for (int c = 0; c < 8; ++c)
                    acc[i][c] += s * w0[c] + n * w1[c] + p * w2[c];
            }
        }
        #pragma unroll
        for (int i = 0; i < 2; ++i)
            #pragma unroll
            for (int c = 0; c < 8; ++c) {
                int d = d0 + c;
                float gama = sigmoidf_(acc[i][c] + gate_b[d]);
                float s = sf[(r0 + i) * ESTR + d];
                float n = ng[(r0 + i) * ESTR + d];
                out[(size_t)(row0 + r0 + i) * ND + d] = gama * s + (1.f - gama) * n;
            }
    }
}

// ---------------------------------------------------------------- launch
extern "C" void kernel_launch(void* const* d_in, const int* in_sizes, int n_in,
                              void* d_out, int out_size, void* d_ws, size_t ws_size,
                              hipStream_t stream)
{
    const int*   nodes     = (const int*)d_in[0];
    const int*   neighbors = (const int*)d_in[1];
    const float* u2e       = (const float*)d_in[2];
    const float* att1_w    = (const float*)d_in[3];
    const float* att1_b    = (const float*)d_in[4];
    const float* att2_w    = (const float*)d_in[5];
    const float* att2_b    = (const float*)d_in[6];
    const float* att3_w    = (const float*)d_in[7];
    const float* att3_b    = (const float*)d_in[8];
    const float* lin1_w    = (const float*)d_in[9];
    const float* lin1_b    = (const float*)d_in[10];
    const float* gate_w    = (const float*)d_in[11];
    const float* gate_b    = (const float*)d_in[12];
    const float* bn_g      = (const float*)d_in[13];
    const float* bn_b      = (const float*)d_in[14];
    const float* bn1_g     = (const float*)d_in[15];
    const float* bn1_b     = (const float*)d_in[16];
    const float* in_w      = (const float*)d_in[17];
    const float* in_b      = (const float*)d_in[18];
    const float* out_w     = (const float*)d_in[19];
    const float* out_b     = (const float*)d_in[20];
    float* out = (float*)d_out;

    float* ws     = (float*)d_ws;
    float* g_hist = ws;                       // 4096*128
    float* h1     = ws + (size_t)NB * ND;     // 4096*128
    float* st     = ws + (size_t)2 * NB * ND; // 4*128 stats

    hipMemsetAsync(st, 0, 4 * ND * sizeof(float), stream);

    k_att<<<NB, 256, 0, stream>>>(nodes, neighbors, u2e,
                                  att1_w, att1_b, att2_w, att2_b,
                                  att3_w, att3_b, lin1_w, lin1_b, g_hist);
    k_colstats<<<NB / 32, 256, 0, stream>>>(g_hist, st, st + 128);
    k_mlp1<<<NB / 32, 256, 0, stream>>>(g_hist, st, st + 128, bn_g, bn_b,
                                        in_w, in_b, h1);
    k_colstats<<<NB / 32, 256, 0, stream>>>(h1, st + 256, st + 384);
    k_final<<<NB / 32, 256, 0, stream>>>(h1, st + 256, st + 384, bn1_g, bn1_b,
                                         out_w, out_b, gate_w, gate_b,
                                         nodes, u2e, out);
}

// Round 3
// 1253.716 us; speedup vs baseline: 1.2794x; 1.2794x over previous
//
#include <hip/hip_runtime.h>
#include <stdint.h>

#define NB 4096      // batch
#define NK 64        // neighbors
#define ND 128       // dim
#define NH 4         // heads
#define ES 132       // bf16 LDS row stride (ushorts) for e/s1 tiles
#define ESW (ES/2)   // 66 dwords per row
#define FS 130       // f32 stride for small kernels

__device__ __forceinline__ float seluf(float x) {
    return 1.0507009873554805f * (x > 0.f ? x : 1.6732632423543772f * (expf(x) - 1.f));
}
__device__ __forceinline__ float sigmoidf_(float x) {
    return 1.f / (1.f + expf(-x));
}
__device__ __forceinline__ uint32_t f2bf2(float a, float b) {
    uint32_t ua = __float_as_uint(a); ua += 0x7fffu + ((ua >> 16) & 1u);
    uint32_t ub = __float_as_uint(b); ub += 0x7fffu + ((ub >> 16) & 1u);
    return (ua >> 16) | (ub & 0xffff0000u);
}
__device__ __forceinline__ float bflo(uint32_t v) { return __uint_as_float(v << 16); }
__device__ __forceinline__ float bfhi(uint32_t v) { return __uint_as_float(v & 0xffff0000u); }
__device__ __forceinline__ float bf2f(uint16_t h) { return __uint_as_float(((uint32_t)h) << 16); }

// ---------------------------------------------------------------- kernel 1
__global__ __launch_bounds__(256, 4)
void k_att(const int* __restrict__ nodes, const int* __restrict__ neighbors,
           const float* __restrict__ u2e,
           const float* __restrict__ att1_w, const float* __restrict__ att1_b,
           const float* __restrict__ att2_w, const float* __restrict__ att2_b,
           const float* __restrict__ att3_w, const float* __restrict__ att3_b,
           const float* __restrict__ lin1_w, const float* __restrict__ lin1_b,
           float* __restrict__ hist_out,
           float* __restrict__ sums, float* __restrict__ sumsq)
{
    __shared__ uint16_t e_sh[NK * ES];      // normalized neighbor embeds, bf16
    __shared__ uint16_t s1_sh[NK * ES];     // att1 output, bf16
    __shared__ float u_sh[ND], un_sh[ND], up_sh[ND], lw_sh[ND], hist_sh[ND];
    __shared__ float alpha_sh[NK], sc_sh[NK], att_sh[NK];
    __shared__ float red_sh[256];
    __shared__ float rnorm_sh;

    const int b = blockIdx.x;
    const int t = threadIdx.x;
    const int lane = t & 63;
    const int wave = t >> 6;

    // ---- gather neighbors + l2norm into LDS (bf16) ----
    for (int k = wave; k < NK; k += 4) {
        int idx = neighbors[b * NK + k];
        float2 v = ((const float2*)(u2e + (size_t)idx * ND))[lane];
        float ss = v.x * v.x + v.y * v.y;
        #pragma unroll
        for (int m = 1; m < 64; m <<= 1) ss += __shfl_xor(ss, m, 64);
        float r = 1.0f / fmaxf(sqrtf(ss), 1e-12f);
        ((uint32_t*)e_sh)[k * ESW + lane] = f2bf2(v.x * r, v.y * r);
    }
    if (t < ND) {
        u_sh[t] = u2e[(size_t)nodes[b] * ND + t];
        hist_sh[t] = 0.f;
    }
    __syncthreads();

    for (int h = 0; h < NH; ++h) {
        // ---- u_n = l2norm(u) ----
        if (wave == 0) {
            float a = u_sh[lane], c = u_sh[lane + 64];
            float ss = a * a + c * c;
            #pragma unroll
            for (int m = 1; m < 64; m <<= 1) ss += __shfl_xor(ss, m, 64);
            if (lane == 0) rnorm_sh = 1.0f / fmaxf(sqrtf(ss), 1e-12f);
        }
        __syncthreads();
        if (t < ND) {
            un_sh[t] = u_sh[t] * rnorm_sh;
            lw_sh[t] = lin1_w[h * ND + t];
        }
        __syncthreads();

        // ---- uproj partials (rank-1 half of att1) ----
        {
            int d = t & 127, half = t >> 7;
            const float* wb = att1_w + (size_t)h * 32768 + (size_t)(ND + half * 64) * ND + d;
            float p = 0.f;
            #pragma unroll 8
            for (int j = 0; j < 64; ++j)
                p += un_sh[half * 64 + j] * wb[j * ND];
            red_sh[t] = p;
        }
        // ---- alpha = sigmoid(e_n . lin1_w + b) + 1 ----
        {
            int k = t >> 2, qd = t & 3;
            const uint32_t* er = (const uint32_t*)e_sh + k * ESW + qd * 16;
            const float* lr = lw_sh + qd * 32;
            float ap = 0.f;
            #pragma unroll 8
            for (int j2 = 0; j2 < 16; ++j2) {
                uint32_t v = er[j2];
                ap += bflo(v) * lr[2 * j2] + bfhi(v) * lr[2 * j2 + 1];
            }
            ap += __shfl_xor(ap, 1, 64);
            ap += __shfl_xor(ap, 2, 64);
            if (qd == 0)
                alpha_sh[k] = sigmoidf_(ap + lin1_b[h]) + 1.0f;
        }
        __syncthreads();
        if (t < ND)
            up_sh[t] = red_sh[t] + red_sh[t + 128] + att1_b[h * ND + t];
        __syncthreads();

        // ---- att1: s1[k][d] = selu(e_n[k] . W1a[:,d] + up[d]) ----
        {
            const int dg = t & 15, kg = t >> 4;
            const int d0 = dg * 8, k0 = kg * 4;
            float acc[4][8] = {};
            const float* W = att1_w + (size_t)h * 32768 + d0;
            const uint32_t* E = (const uint32_t*)e_sh;
            #pragma unroll 2
            for (int j = 0; j < ND; j += 2) {
                float4 a0 = *(const float4*)(W + (size_t)j * ND);
                float4 b0 = *(const float4*)(W + (size_t)j * ND + 4);
                float4 a1 = *(const float4*)(W + (size_t)(j + 1) * ND);
                float4 b1 = *(const float4*)(W + (size_t)(j + 1) * ND + 4);
                float w0[8] = {a0.x, a0.y, a0.z, a0.w, b0.x, b0.y, b0.z, b0.w};
                float w1[8] = {a1.x, a1.y, a1.z, a1.w, b1.x, b1.y, b1.z, b1.w};
                uint32_t ev[4];
                #pragma unroll
                for (int i = 0; i < 4; ++i) ev[i] = E[(k0 + i) * ESW + (j >> 1)];
                #pragma unroll
                for (int i = 0; i < 4; ++i) {
                    float e0 = bflo(ev[i]), e1 = bfhi(ev[i]);
                    #pragma unroll
                    for (int c = 0; c < 8; ++c) {
                        acc[i][c] += e0 * w0[c];
                        acc[i][c] += e1 * w1[c];
                    }
                }
            }
            #pragma unroll
            for (int i = 0; i < 4; ++i) {
                uint32_t* row = (uint32_t*)s1_sh + (k0 + i) * ESW + (d0 >> 1);
                #pragma unroll
                for (int c = 0; c < 4; ++c) {
                    float v0 = seluf(acc[i][2 * c]     + up_sh[d0 + 2 * c]);
                    float v1 = seluf(acc[i][2 * c + 1] + up_sh[d0 + 2 * c + 1]);
                    row[c] = f2bf2(v0, v1);
                }
            }
        }
        __syncthreads();

        // ---- att2 (+bias, selu) then att3 dot -> sc[k] ----
        {
            const int cg = t & 7, kg2 = t >> 3;
            const int c0 = cg * 4, k0 = kg2 * 2;
            float acc[2][4] = {};
            const float* W2 = att2_w + h * 4096 + c0;
            const uint32_t* S = (const uint32_t*)s1_sh;
            #pragma unroll 2
            for (int d = 0; d < ND; d += 2) {
                float4 wA = *(const float4*)(W2 + (size_t)d * 32);
                float4 wB = *(const float4*)(W2 + (size_t)(d + 1) * 32);
                uint32_t sv0 = S[k0 * ESW + (d >> 1)];
                uint32_t sv1 = S[(k0 + 1) * ESW + (d >> 1)];
                float e00 = bflo(sv0), e01 = bfhi(sv0);
                float e10 = bflo(sv1), e11 = bfhi(sv1);
                acc[0][0] += e00 * wA.x + e01 * wB.x;
                acc[0][1] += e00 * wA.y + e01 * wB.y;
                acc[0][2] += e00 * wA.z + e01 * wB.z;
                acc[0][3] += e00 * wA.w + e01 * wB.w;
                acc[1][0] += e10 * wA.x + e11 * wB.x;
                acc[1][1] += e10 * wA.y + e11 * wB.y;
                acc[1][2] += e10 * wA.z + e11 * wB.z;
                acc[1][3] += e10 * wA.w + e11 * wB.w;
            }
            float p0 = 0.f, p1 = 0.f;
            #pragma unroll
            for (int c = 0; c < 4; ++c) {
                float w3 = att3_w[h * 32 + c0 + c];
                float b2 = att2_b[h * 32 + c0 + c];
                p0 += seluf(acc[0][c] + b2) * w3;
                p1 += seluf(acc[1][c] + b2) * w3;
            }
            p0 += __shfl_xor(p0, 1, 64); p0 += __shfl_xor(p0, 2, 64); p0 += __shfl_xor(p0, 4, 64);
            p1 += __shfl_xor(p1, 1, 64); p1 += __shfl_xor(p1, 2, 64); p1 += __shfl_xor(p1, 4, 64);
            if (cg == 0) {
                float b3 = att3_b[h];
                sc_sh[k0]     = p0 + b3;
                sc_sh[k0 + 1] = p1 + b3;
            }
        }
        __syncthreads();

        // ---- entmax: Newton on f(tau)=sum max(xs-tau,0)^q - 1 (convex, from below) ----
        if (wave == 0) {
            float x   = sc_sh[lane];
            float am1 = alpha_sh[lane] - 1.0f;
            float q   = 1.0f / am1;
            float em1 = q - 1.0f;
            float xs  = x * am1;
            float mx = xs;
            #pragma unroll
            for (int m = 1; m < 64; m <<= 1) mx = fmaxf(mx, __shfl_xor(mx, m, 64));
            float tau = mx - 1.0f;
            for (int it = 0; it < 10; ++it) {
                float tt = xs - tau;
                bool pos = tt > 0.f;
                float lg = log2f(pos ? tt : 1.f);
                float p  = pos ? exp2f(q * lg) : 0.f;
                float dp = pos ? q * exp2f(em1 * lg) : 0.f;
                float s0 = p, s1 = dp;
                #pragma unroll
                for (int m = 1; m < 64; m <<= 1) {
                    s0 += __shfl_xor(s0, m, 64);
                    s1 += __shfl_xor(s1, m, 64);
                }
                tau += (s0 - 1.0f) / fmaxf(s1, 1e-30f);
                tau = fminf(tau, mx - 1e-6f);
            }
            float tt = xs - tau;
            bool pos = tt > 0.f;
            float p = pos ? exp2f(q * log2f(pos ? tt : 1.f)) : 0.f;
            float s0 = p;
            #pragma unroll
            for (int m = 1; m < 64; m <<= 1) s0 += __shfl_xor(s0, m, 64);
            att_sh[lane] = p / s0;
        }
        __syncthreads();

        // ---- pool: u[d] = sum_k e_n[k][d] * att[k]; hist += u ----
        {
            int d = t & 127, half = t >> 7;
            const uint16_t* er = e_sh + (half * 32) * ES + d;
            float p = 0.f;
            #pragma unroll 8
            for (int k = 0; k < 32; ++k)
                p += bf2f(er[k * ES]) * att_sh[half * 32 + k];
            red_sh[t] = p;
        }
        __syncthreads();
        if (t < ND) {
            float un = red_sh[t] + red_sh[t + 128];
            u_sh[t] = un;
            hist_sh[t] += un;
        }
        __syncthreads();
    }
    if (t < ND) {
        float hv = hist_sh[t] * 0.25f;
        hist_out[(size_t)b * ND + t] = hv;
        atomicAdd(&sums[t], hv);
        atomicAdd(&sumsq[t], hv * hv);
    }
}

// ---------------------------------------------------------------- column stats (for h1)
__global__ __launch_bounds__(256)
void k_colstats(const float* __restrict__ x,
                float* __restrict__ sums, float* __restrict__ sumsq)
{
    __shared__ float rs[256], rq[256];
    int t = threadIdx.x;
    int d = t & 127, rh = t >> 7;
    int row0 = blockIdx.x * 32;
    float s = 0.f, q = 0.f;
    #pragma unroll 4
    for (int i = 0; i < 16; ++i) {
        int r = row0 + rh * 16 + i;
        float v = x[(size_t)r * ND + d];
        s += v; q += v * v;
    }
    rs[t] = s; rq[t] = q;
    __syncthreads();
    if (t < ND) {
        atomicAdd(&sums[d],  rs[t] + rs[t + 128]);
        atomicAdd(&sumsq[d], rq[t] + rq[t + 128]);
    }
}

// ---------------------------------------------------------------- h1 = selu(bn(hist) @ in_w + in_b)
__global__ __launch_bounds__(256)
void k_mlp1(const float* __restrict__ hist,
            const float* __restrict__ sums, const float* __restrict__ sumsq,
            const float* __restrict__ bn_g, const float* __restrict__ bn_b,
            const float* __restrict__ in_w, const float* __restrict__ in_b,
            float* __restrict__ h1out)
{
    __shared__ float xh[32 * FS];
    int t = threadIdx.x;
    int row0 = blockIdx.x * 32;
    for (int i = t; i < 32 * ND; i += 256) {
        int r = i >> 7, d = i & 127;
        float m  = sums[d]  * (1.f / 4096.f);
        float vv = sumsq[d] * (1.f / 4096.f) - m * m;
        float sc = bn_g[d] * rsqrtf(vv + 1e-5f);
        float sh = bn_b[d] - m * sc;
        xh[r * FS + d] = hist[(size_t)(row0 + r) * ND + d] * sc + sh;
    }
    __syncthreads();
    int dg = t & 15, rg = t >> 4;
    int d0 = dg * 8, r0 = rg * 2;
    float acc[2][8] = {};
    for (int j = 0; j < ND; ++j) {
        const float* wr = in_w + (size_t)j * ND + d0;
        float4 wa = *(const float4*)wr, wb = *(const float4*)(wr + 4);
        float w[8] = {wa.x, wa.y, wa.z, wa.w, wb.x, wb.y, wb.z, wb.w};
        float e0 = xh[r0 * FS + j], e1 = xh[(r0 + 1) * FS + j];
        #pragma unroll
        for (int c = 0; c < 8; ++c) { acc[0][c] += e0 * w[c]; acc[1][c] += e1 * w[c]; }
    }
    #pragma unroll
    for (int i = 0; i < 2; ++i)
        #pragma unroll
        for (int c = 0; c < 8; ++c) {
            int d = d0 + c;
            h1out[(size_t)(row0 + r0 + i) * ND + d] = seluf(acc[i][c] + in_b[d]);
        }
}

// ---------------------------------------------------------------- final: neigh = bn1(h1)@out_w+b; gated combine
__global__ __launch_bounds__(256)
void k_final(const float* __restrict__ h1,
             const float* __restrict__ sums1, const float* __restrict__ sumsq1,
             const float* __restrict__ bn1_g, const float* __restrict__ bn1_b,
             const float* __restrict__ out_w, const float* __restrict__ out_b,
             const float* __restrict__ gate_w, const float* __restrict__ gate_b,
             const int* __restrict__ nodes, const float* __restrict__ u2e,
             float* __restrict__ out)
{
    __shared__ float xh[32 * FS];
    __shared__ float sf[32 * FS];
    __shared__ float ng[32 * FS];
    int t = threadIdx.x;
    int row0 = blockIdx.x * 32;
    for (int i = t; i < 32 * ND; i += 256) {
        int r = i >> 7, d = i & 127;
        float m  = sums1[d]  * (1.f / 4096.f);
        float vv = sumsq1[d] * (1.f / 4096.f) - m * m;
        float sc = bn1_g[d] * rsqrtf(vv + 1e-5f);
        float sh = bn1_b[d] - m * sc;
        xh[r * FS + d] = h1[(size_t)(row0 + r) * ND + d] * sc + sh;
        sf[r * FS + d] = u2e[(size_t)nodes[row0 + r] * ND + d];
    }
    __syncthreads();
    int dg = t & 15, rg = t >> 4;
    int d0 = dg * 8, r0 = rg * 2;
    {
        float acc[2][8] = {};
        for (int j = 0; j < ND; ++j) {
            const float* wr = out_w + (size_t)j * ND + d0;
            float4 wa = *(const float4*)wr, wb = *(const float4*)(wr + 4);
            float w[8] = {wa.x, wa.y, wa.z, wa.w, wb.x, wb.y, wb.z, wb.w};
            float e0 = xh[r0 * FS + j], e1 = xh[(r0 + 1) * FS + j];
            #pragma unroll
            for (int c = 0; c < 8; ++c) { acc[0][c] += e0 * w[c]; acc[1][c] += e1 * w[c]; }
        }
        #pragma unroll
        for (int i = 0; i < 2; ++i)
            #pragma unroll
            for (int c = 0; c < 8; ++c)
                ng[(r0 + i) * FS + d0 + c] = acc[i][c] + out_b[d0 + c];
    }
    __syncthreads();
    {
        float acc[2][8] = {};
        for (int j = 0; j < ND; ++j) {
            const float* g0 = gate_w + (size_t)j * ND + d0;
            const float* g1 = gate_w + (size_t)(ND + j) * ND + d0;
            const float* g2 = gate_w + (size_t)(2 * ND + j) * ND + d0;
            float4 a0 = *(const float4*)g0, b0 = *(const float4*)(g0 + 4);
            float4 a1 = *(const float4*)g1, b1 = *(const float4*)(g1 + 4);
            float4 a2 = *(const float4*)g2, b2 = *(const float4*)(g2 + 4);
            float w0[8] = {a0.x, a0.y, a0.z, a0.w, b0.x, b0.y, b0.z, b0.w};
            float w1[8] = {a1.x, a1.y, a1.z, a1.w, b1.x, b1.y, b1.z, b1.w};
            float w2[8] = {a2.x, a2.y, a2.z, a2.w, b2.x, b2.y, b2.z, b2.w};
            #pragma unroll
            for (int i = 0; i < 2; ++i) {
                float s = sf[(r0 + i) * FS + j];
                float n = ng[(r0 + i) * FS + j];
                float p = s * n;
                #pragma unroll
                for (int c = 0; c < 8; ++c)
                    acc[i][c] += s * w0[c] + n * w1[c] + p * w2[c];
            }
        }
        #pragma unroll
        for (int i = 0; i < 2; ++i)
            #pragma unroll
            for (int c = 0; c < 8; ++c) {
                int d = d0 + c;
                float gama = sigmoidf_(acc[i][c] + gate_b[d]);
                float s = sf[(r0 + i) * FS + d];
                float n = ng[(r0 + i) * FS + d];
                out[(size_t)(row0 + r0 + i) * ND + d] = gama * s + (1.f - gama) * n;
            }
    }
}

// ---------------------------------------------------------------- launch
extern "C" void kernel_launch(void* const* d_in, const int* in_sizes, int n_in,
                              void* d_out, int out_size, void* d_ws, size_t ws_size,
                              hipStream_t stream)
{
    const int*   nodes     = (const int*)d_in[0];
    const int*   neighbors = (const int*)d_in[1];
    const float* u2e       = (const float*)d_in[2];
    const float* att1_w    = (const float*)d_in[3];
    const float* att1_b    = (const float*)d_in[4];
    const float* att2_w    = (const float*)d_in[5];
    const float* att2_b    = (const float*)d_in[6];
    const float* att3_w    = (const float*)d_in[7];
    const float* att3_b    = (const float*)d_in[8];
    const float* lin1_w    = (const float*)d_in[9];
    const float* lin1_b    = (const float*)d_in[10];
    const float* gate_w    = (const float*)d_in[11];
    const float* gate_b    = (const float*)d_in[12];
    const float* bn_g      = (const float*)d_in[13];
    const float* bn_b      = (const float*)d_in[14];
    const float* bn1_g     = (const float*)d_in[15];
    const float* bn1_b     = (const float*)d_in[16];
    const float* in_w      = (const float*)d_in[17];
    const float* in_b      = (const float*)d_in[18];
    const float* out_w     = (const float*)d_in[19];
    const float* out_b     = (const float*)d_in[20];
    float* out = (float*)d_out;

    float* ws     = (float*)d_ws;
    float* g_hist = ws;                       // 4096*128
    float* h1     = ws + (size_t)NB * ND;     // 4096*128
    float* st     = ws + (size_t)2 * NB * ND; // 4*128 stats

    (void)hipMemsetAsync(st, 0, 4 * ND * sizeof(float), stream);

    k_att<<<NB, 256, 0, stream>>>(nodes, neighbors, u2e,
                                  att1_w, att1_b, att2_w, att2_b,
                                  att3_w, att3_b, lin1_w, lin1_b,
                                  g_hist, st, st + 128);
    k_mlp1<<<NB / 32, 256, 0, stream>>>(g_hist, st, st + 128, bn_g, bn_b,
                                        in_w, in_b, h1);
    k_colstats<<<NB / 32, 256, 0, stream>>>(h1, st + 256, st + 384);
    k_final<<<NB / 32, 256, 0, stream>>>(h1, st + 256, st + 384, bn1_g, bn1_b,
                                         out_w, out_b, gate_w, gate_b,
                                         nodes, u2e, out);
}

// Round 4
// 630.416 us; speedup vs baseline: 2.5444x; 1.9887x over previous
//
#include <hip/hip_runtime.h>
#include <stdint.h>

#define NB 4096      // batch
#define NK 64        // neighbors
#define ND 128       // dim
#define NH 4         // heads
#define ES 136       // bf16 LDS row stride (ushorts): 272B, 16B-aligned rows
#define ESW (ES/2)   // 68 dwords per row
#define FS 130       // f32 stride for small kernels
#define MR 16        // row tile for mlp/final kernels

typedef __attribute__((ext_vector_type(8))) short bf16x8;
typedef __attribute__((ext_vector_type(4))) float f32x4;

__device__ __forceinline__ float seluf(float x) {
    return 1.0507009873554805f * (x > 0.f ? x : 1.6732632423543772f * (expf(x) - 1.f));
}
__device__ __forceinline__ float sigmoidf_(float x) {
    return 1.f / (1.f + expf(-x));
}
__device__ __forceinline__ uint32_t f2bf2(float a, float b) {
    uint32_t ua = __float_as_uint(a); ua += 0x7fffu + ((ua >> 16) & 1u);
    uint32_t ub = __float_as_uint(b); ub += 0x7fffu + ((ub >> 16) & 1u);
    return (ua >> 16) | (ub & 0xffff0000u);
}
__device__ __forceinline__ uint16_t bf1(float v) {
    uint32_t u = __float_as_uint(v); u += 0x7fffu + ((u >> 16) & 1u);
    return (uint16_t)(u >> 16);
}
__device__ __forceinline__ float bflo(uint32_t v) { return __uint_as_float(v << 16); }
__device__ __forceinline__ float bfhi(uint32_t v) { return __uint_as_float(v & 0xffff0000u); }
__device__ __forceinline__ float bf2f(uint16_t h) { return __uint_as_float(((uint32_t)h) << 16); }

// ------------------------------------------------- prep: transpose weights to bf16 K-major
// wt1[h][n][k] = att1_w[h][k][n]  (k<128, n<128)   wt2[h][c][d] = att2_w[h][d][c]
__global__ __launch_bounds__(256)
void k_prep(const float* __restrict__ att1_w, const float* __restrict__ att2_w,
            uint16_t* __restrict__ wt1, uint16_t* __restrict__ wt2)
{
    const int h = blockIdx.x;
    const int t = threadIdx.x;
    {
        int n = t >> 1, kh = t & 1;
        for (int k0 = 0; k0 < 64; ++k0) {
            int k = k0 * 2 + kh;
            float v = att1_w[(size_t)h * 32768 + (size_t)k * ND + n];
            float vo = __shfl_xor(v, 1, 64);
            if (kh == 0)
                ((uint32_t*)wt1)[((size_t)h * ND + n) * 64 + k0] = f2bf2(v, vo);
        }
    }
    {
        int c = t & 31, dh = t >> 5;
        for (int d0 = 0; d0 < 16; ++d0) {
            int d = d0 * 8 + dh;
            float v = att2_w[(size_t)h * 4096 + (size_t)d * 32 + c];
            float vo = __shfl_xor(v, 32, 64);
            if ((dh & 1) == 0)
                ((uint32_t*)wt2)[((size_t)h * 32 + c) * 64 + d0 * 4 + (dh >> 1)] = f2bf2(v, vo);
        }
    }
}

// ---------------------------------------------------------------- kernel 1
__global__ __launch_bounds__(256, 4)
void k_att(const int* __restrict__ nodes, const int* __restrict__ neighbors,
           const float* __restrict__ u2e,
           const float* __restrict__ att1_w, const float* __restrict__ att1_b,
           const float* __restrict__ att2_b,
           const float* __restrict__ att3_w, const float* __restrict__ att3_b,
           const float* __restrict__ lin1_w, const float* __restrict__ lin1_b,
           const uint16_t* __restrict__ wt1, const uint16_t* __restrict__ wt2,
           float* __restrict__ hist_out,
           float* __restrict__ sums, float* __restrict__ sumsq)
{
    __shared__ alignas(16) uint16_t e_sh[NK * ES];   // normalized neighbor embeds, bf16
    __shared__ alignas(16) uint16_t s1_sh[NK * ES];  // att1 output, bf16
    __shared__ float u_sh[ND], un_sh[ND], up_sh[ND], lw_sh[ND], hist_sh[ND];
    __shared__ float alpha_sh[NK], sc_sh[NK], att_sh[NK];
    __shared__ float red_sh[256];
    __shared__ float rnorm_sh;

    const int b = blockIdx.x;
    const int t = threadIdx.x;
    const int lane = t & 63;
    const int wave = t >> 6;
    const int lh = lane & 15;   // fragment col / row-in-tile
    const int lg = lane >> 4;   // k-group

    // ---- gather neighbors + l2norm into LDS (bf16) ----
    for (int k = wave; k < NK; k += 4) {
        int idx = neighbors[b * NK + k];
        float2 v = ((const float2*)(u2e + (size_t)idx * ND))[lane];
        float ss = v.x * v.x + v.y * v.y;
        #pragma unroll
        for (int m = 1; m < 64; m <<= 1) ss += __shfl_xor(ss, m, 64);
        float r = 1.0f / fmaxf(sqrtf(ss), 1e-12f);
        ((uint32_t*)e_sh)[k * ESW + lane] = f2bf2(v.x * r, v.y * r);
    }
    if (t < ND) {
        u_sh[t] = u2e[(size_t)nodes[b] * ND + t];
        hist_sh[t] = 0.f;
    }
    __syncthreads();

    for (int h = 0; h < NH; ++h) {
        // ---- u_n = l2norm(u) ----
        if (wave == 0) {
            float a = u_sh[lane], c = u_sh[lane + 64];
            float ss = a * a + c * c;
            #pragma unroll
            for (int m = 1; m < 64; m <<= 1) ss += __shfl_xor(ss, m, 64);
            if (lane == 0) rnorm_sh = 1.0f / fmaxf(sqrtf(ss), 1e-12f);
        }
        __syncthreads();
        if (t < ND) {
            un_sh[t] = u_sh[t] * rnorm_sh;
            lw_sh[t] = lin1_w[h * ND + t];
        }
        __syncthreads();

        // ---- uproj partials (rank-1 half of att1, VALU) ----
        {
            int d = t & 127, half = t >> 7;
            const float* wb = att1_w + (size_t)h * 32768 + (size_t)(ND + half * 64) * ND + d;
            float p = 0.f;
            #pragma unroll 8
            for (int j = 0; j < 64; ++j)
                p += un_sh[half * 64 + j] * wb[j * ND];
            red_sh[t] = p;
        }
        // ---- alpha = sigmoid(e_n . lin1_w + b) + 1 ----
        {
            int k = t >> 2, qd = t & 3;
            const uint32_t* er = (const uint32_t*)e_sh + k * ESW + qd * 16;
            const float* lr = lw_sh + qd * 32;
            float ap = 0.f;
            #pragma unroll 8
            for (int j2 = 0; j2 < 16; ++j2) {
                uint32_t v = er[j2];
                ap += bflo(v) * lr[2 * j2] + bfhi(v) * lr[2 * j2 + 1];
            }
            ap += __shfl_xor(ap, 1, 64);
            ap += __shfl_xor(ap, 2, 64);
            if (qd == 0)
                alpha_sh[k] = sigmoidf_(ap + lin1_b[h]) + 1.0f;
        }
        __syncthreads();
        if (t < ND)
            up_sh[t] = red_sh[t] + red_sh[t + 128] + att1_b[h * ND + t];
        __syncthreads();

        // ---- att1 via MFMA: C[64k][128n] = E[64,128] @ W1a[128,128] ----
        // wave w owns n in [w*32, w*32+32)
        {
            const uint16_t* WB = wt1 + ((size_t)h * ND + wave * 32) * ND;
            bf16x8 B[4][2];
            #pragma unroll
            for (int kk = 0; kk < 4; ++kk)
                #pragma unroll
                for (int nt = 0; nt < 2; ++nt)
                    B[kk][nt] = *(const bf16x8*)(WB + (nt * 16 + lh) * ND + kk * 32 + lg * 8);
            f32x4 z = {0.f, 0.f, 0.f, 0.f};
            f32x4 acc[4][2] = {{z, z}, {z, z}, {z, z}, {z, z}};
            #pragma unroll
            for (int mt = 0; mt < 4; ++mt) {
                #pragma unroll
                for (int kk = 0; kk < 4; ++kk) {
                    bf16x8 A = *(const bf16x8*)(e_sh + (mt * 16 + lh) * ES + kk * 32 + lg * 8);
                    acc[mt][0] = __builtin_amdgcn_mfma_f32_16x16x32_bf16(A, B[kk][0], acc[mt][0], 0, 0, 0);
                    acc[mt][1] = __builtin_amdgcn_mfma_f32_16x16x32_bf16(A, B[kk][1], acc[mt][1], 0, 0, 0);
                }
            }
            float up0 = up_sh[wave * 32 + lh];
            float up1 = up_sh[wave * 32 + 16 + lh];
            #pragma unroll
            for (int mt = 0; mt < 4; ++mt)
                #pragma unroll
                for (int nt = 0; nt < 2; ++nt) {
                    float upv = nt ? up1 : up0;
                    #pragma unroll
                    for (int r = 0; r < 4; ++r) {
                        float v = seluf(acc[mt][nt][r] + upv);
                        s1_sh[(mt * 16 + lg * 4 + r) * ES + wave * 32 + nt * 16 + lh] = bf1(v);
                    }
                }
        }
        __syncthreads();

        // ---- att2 via MFMA: C2[64k][32c] = S1[64,128] @ W2[128,32]; then selu+att3 dot ----
        // wave w owns rows [w*16, w*16+16)
        {
            const uint16_t* WB2 = wt2 + (size_t)h * 32 * ND;
            bf16x8 B2[4][2];
            #pragma unroll
            for (int kk = 0; kk < 4; ++kk)
                #pragma unroll
                for (int nt = 0; nt < 2; ++nt)
                    B2[kk][nt] = *(const bf16x8*)(WB2 + (nt * 16 + lh) * ND + kk * 32 + lg * 8);
            f32x4 z = {0.f, 0.f, 0.f, 0.f};
            f32x4 acc2[2] = {z, z};
            #pragma unroll
            for (int kk = 0; kk < 4; ++kk) {
                bf16x8 A = *(const bf16x8*)(s1_sh + (wave * 16 + lh) * ES + kk * 32 + lg * 8);
                acc2[0] = __builtin_amdgcn_mfma_f32_16x16x32_bf16(A, B2[kk][0], acc2[0], 0, 0, 0);
                acc2[1] = __builtin_amdgcn_mfma_f32_16x16x32_bf16(A, B2[kk][1], acc2[1], 0, 0, 0);
            }
            float w3a = att3_w[h * 32 + lh],      b2a = att2_b[h * 32 + lh];
            float w3b = att3_w[h * 32 + 16 + lh], b2b = att2_b[h * 32 + 16 + lh];
            float b3 = att3_b[h];
            #pragma unroll
            for (int r = 0; r < 4; ++r) {
                float v = seluf(acc2[0][r] + b2a) * w3a + seluf(acc2[1][r] + b2b) * w3b;
                v += __shfl_xor(v, 1, 64);
                v += __shfl_xor(v, 2, 64);
                v += __shfl_xor(v, 4, 64);
                v += __shfl_xor(v, 8, 64);
                if (lh == 0)
                    sc_sh[wave * 16 + lg * 4 + r] = v + b3;
            }
        }
        __syncthreads();

        // ---- entmax: Newton on f(tau)=sum max(xs-tau,0)^q - 1 ----
        if (wave == 0) {
            float x   = sc_sh[lane];
            float am1 = alpha_sh[lane] - 1.0f;
            float q   = 1.0f / am1;
            float em1 = q - 1.0f;
            float xs  = x * am1;
            float mx = xs;
            #pragma unroll
            for (int m = 1; m < 64; m <<= 1) mx = fmaxf(mx, __shfl_xor(mx, m, 64));
            float tau = mx - 1.0f;
            for (int it = 0; it < 10; ++it) {
                float tt = xs - tau;
                bool pos = tt > 0.f;
                float lg2 = log2f(pos ? tt : 1.f);
                float p  = pos ? exp2f(q * lg2) : 0.f;
                float dp = pos ? q * exp2f(em1 * lg2) : 0.f;
                float s0 = p, s1 = dp;
                #pragma unroll
                for (int m = 1; m < 64; m <<= 1) {
                    s0 += __shfl_xor(s0, m, 64);
                    s1 += __shfl_xor(s1, m, 64);
                }
                tau += (s0 - 1.0f) / fmaxf(s1, 1e-30f);
                tau = fminf(tau, mx - 1e-6f);
            }
            float tt = xs - tau;
            bool pos = tt > 0.f;
            float p = pos ? exp2f(q * log2f(pos ? tt : 1.f)) : 0.f;
            float s0 = p;
            #pragma unroll
            for (int m = 1; m < 64; m <<= 1) s0 += __shfl_xor(s0, m, 64);
            att_sh[lane] = p / s0;
        }
        __syncthreads();

        // ---- pool: u[d] = sum_k e_n[k][d] * att[k]; hist += u ----
        {
            int d = t & 127, half = t >> 7;
            const uint16_t* er = e_sh + (half * 32) * ES + d;
            float p = 0.f;
            #pragma unroll 8
            for (int k = 0; k < 32; ++k)
                p += bf2f(er[k * ES]) * att_sh[half * 32 + k];
            red_sh[t] = p;
        }
        __syncthreads();
        if (t < ND) {
            float un = red_sh[t] + red_sh[t + 128];
            u_sh[t] = un;
            hist_sh[t] += un;
        }
        __syncthreads();
    }
    if (t < ND) {
        float hv = hist_sh[t] * 0.25f;
        hist_out[(size_t)b * ND + t] = hv;
        atomicAdd(&sums[t], hv);
        atomicAdd(&sumsq[t], hv * hv);
    }
}

// ---------------------------------------------------------------- h1 = selu(bn(hist) @ in_w + in_b), fused h1 stats
__global__ __launch_bounds__(256)
void k_mlp1(const float* __restrict__ hist,
            const float* __restrict__ sums, const float* __restrict__ sumsq,
            const float* __restrict__ bn_g, const float* __restrict__ bn_b,
            const float* __restrict__ in_w, const float* __restrict__ in_b,
            float* __restrict__ h1out,
            float* __restrict__ sums1, float* __restrict__ sumsq1)
{
    __shared__ float xh[MR * FS];
    int t = threadIdx.x;
    int row0 = blockIdx.x * MR;
    for (int i = t; i < MR * ND; i += 256) {
        int r = i >> 7, d = i & 127;
        float m  = sums[d]  * (1.f / 4096.f);
        float vv = sumsq[d] * (1.f / 4096.f) - m * m;
        float sc = bn_g[d] * rsqrtf(vv + 1e-5f);
        float sh = bn_b[d] - m * sc;
        xh[r * FS + d] = hist[(size_t)(row0 + r) * ND + d] * sc + sh;
    }
    __syncthreads();
    int dg = t & 15, rg = t >> 4;
    int d0 = dg * 8;
    float acc[8] = {};
    float ebuf;
    for (int j = 0; j < ND; ++j) {
        const float* wr = in_w + (size_t)j * ND + d0;
        float4 wa = *(const float4*)wr, wb = *(const float4*)(wr + 4);
        float w[8] = {wa.x, wa.y, wa.z, wa.w, wb.x, wb.y, wb.z, wb.w};
        ebuf = xh[rg * FS + j];
        #pragma unroll
        for (int c = 0; c < 8; ++c) acc[c] += ebuf * w[c];
    }
    float hv[8];
    #pragma unroll
    for (int c = 0; c < 8; ++c) {
        hv[c] = seluf(acc[c] + in_b[d0 + c]);
        h1out[(size_t)(row0 + rg) * ND + d0 + c] = hv[c];
    }
    __syncthreads();
    #pragma unroll
    for (int c = 0; c < 8; ++c) xh[rg * FS + d0 + c] = hv[c];
    __syncthreads();
    if (t < ND) {
        float s = 0.f, q = 0.f;
        #pragma unroll
        for (int r = 0; r < MR; ++r) {
            float v = xh[r * FS + t];
            s += v; q += v * v;
        }
        atomicAdd(&sums1[t], s);
        atomicAdd(&sumsq1[t], q);
    }
}

// ---------------------------------------------------------------- final: neigh = bn1(h1)@out_w+b; gated combine
__global__ __launch_bounds__(256)
void k_final(const float* __restrict__ h1,
             const float* __restrict__ sums1, const float* __restrict__ sumsq1,
             const float* __restrict__ bn1_g, const float* __restrict__ bn1_b,
             const float* __restrict__ out_w, const float* __restrict__ out_b,
             const float* __restrict__ gate_w, const float* __restrict__ gate_b,
             const int* __restrict__ nodes, const float* __restrict__ u2e,
             float* __restrict__ out)
{
    __shared__ float xh[MR * FS];
    __shared__ float sf[MR * FS];
    __shared__ float ng[MR * FS];
    int t = threadIdx.x;
    int row0 = blockIdx.x * MR;
    for (int i = t; i < MR * ND; i += 256) {
        int r = i >> 7, d = i & 127;
        float m  = sums1[d]  * (1.f / 4096.f);
        float vv = sumsq1[d] * (1.f / 4096.f) - m * m;
        float sc = bn1_g[d] * rsqrtf(vv + 1e-5f);
        float sh = bn1_b[d] - m * sc;
        xh[r * FS + d] = h1[(size_t)(row0 + r) * ND + d] * sc + sh;
        sf[r * FS + d] = u2e[(size_t)nodes[row0 + r] * ND + d];
    }
    __syncthreads();
    int dg = t & 15, rg = t >> 4;
    int d0 = dg * 8;
    {
        float acc[8] = {};
        for (int j = 0; j < ND; ++j) {
            const float* wr = out_w + (size_t)j * ND + d0;
            float4 wa = *(const float4*)wr, wb = *(const float4*)(wr + 4);
            float w[8] = {wa.x, wa.y, wa.z, wa.w, wb.x, wb.y, wb.z, wb.w};
            float e0 = xh[rg * FS + j];
            #pragma unroll
            for (int c = 0; c < 8; ++c) acc[c] += e0 * w[c];
        }
        #pragma unroll
        for (int c = 0; c < 8; ++c)
            ng[rg * FS + d0 + c] = acc[c] + out_b[d0 + c];
    }
    __syncthreads();
    {
        float acc[8] = {};
        for (int j = 0; j < ND; ++j) {
            const float* g0 = gate_w + (size_t)j * ND + d0;
            const float* g1 = gate_w + (size_t)(ND + j) * ND + d0;
            const float* g2 = gate_w + (size_t)(2 * ND + j) * ND + d0;
            float4 a0 = *(const float4*)g0, b0 = *(const float4*)(g0 + 4);
            float4 a1 = *(const float4*)g1, b1 = *(const float4*)(g1 + 4);
            float4 a2 = *(const float4*)g2, b2 = *(const float4*)(g2 + 4);
            float w0[8] = {a0.x, a0.y, a0.z, a0.w, b0.x, b0.y, b0.z, b0.w};
            float w1[8] = {a1.x, a1.y, a1.z, a1.w, b1.x, b1.y, b1.z, b1.w};
            float w2[8] = {a2.x, a2.y, a2.z, a2.w, b2.x, b2.y, b2.z, b2.w};
            float s = sf[rg * FS + j];
            float n = ng[rg * FS + j];
            float p = s * n;
            #pragma unroll
            for (int c = 0; c < 8; ++c)
                acc[c] += s * w0[c] + n * w1[c] + p * w2[c];
        }
        #pragma unroll
        for (int c = 0; c < 8; ++c) {
            int d = d0 + c;
            float gama = sigmoidf_(acc[c] + gate_b[d]);
            float s = sf[rg * FS + d];
            float n = ng[rg * FS + d];
            out[(size_t)(row0 + rg) * ND + d] = gama * s + (1.f - gama) * n;
        }
    }
}

// ---------------------------------------------------------------- launch
extern "C" void kernel_launch(void* const* d_in, const int* in_sizes, int n_in,
                              void* d_out, int out_size, void* d_ws, size_t ws_size,
                              hipStream_t stream)
{
    const int*   nodes     = (const int*)d_in[0];
    const int*   neighbors = (const int*)d_in[1];
    const float* u2e       = (const float*)d_in[2];
    const float* att1_w    = (const float*)d_in[3];
    const float* att1_b    = (const float*)d_in[4];
    const float* att2_w    = (const float*)d_in[5];
    const float* att2_b    = (const float*)d_in[6];
    const float* att3_w    = (const float*)d_in[7];
    const float* att3_b    = (const float*)d_in[8];
    const float* lin1_w    = (const float*)d_in[9];
    const float* lin1_b    = (const float*)d_in[10];
    const float* gate_w    = (const float*)d_in[11];
    const float* gate_b    = (const float*)d_in[12];
    const float* bn_g      = (const float*)d_in[13];
    const float* bn_b      = (const float*)d_in[14];
    const float* bn1_g     = (const float*)d_in[15];
    const float* bn1_b     = (const float*)d_in[16];
    const float* in_w      = (const float*)d_in[17];
    const float* in_b      = (const float*)d_in[18];
    const float* out_w     = (const float*)d_in[19];
    const float* out_b     = (const float*)d_in[20];
    float* out = (float*)d_out;

    float* ws     = (float*)d_ws;
    float* g_hist = ws;                             // 4096*128 f32
    float* h1     = ws + (size_t)NB * ND;           // 4096*128 f32
    float* st     = ws + (size_t)2 * NB * ND;       // 512 f32 stats
    uint16_t* wt1 = (uint16_t*)(ws + (size_t)2 * NB * ND + 512);  // 4*128*128 bf16
    uint16_t* wt2 = wt1 + (size_t)NH * ND * ND;                   // 4*32*128 bf16

    (void)hipMemsetAsync(st, 0, 512 * sizeof(float), stream);

    k_prep<<<NH, 256, 0, stream>>>(att1_w, att2_w, wt1, wt2);
    k_att<<<NB, 256, 0, stream>>>(nodes, neighbors, u2e,
                                  att1_w, att1_b, att2_b,
                                  att3_w, att3_b, lin1_w, lin1_b,
                                  wt1, wt2,
                                  g_hist, st, st + 128);
    k_mlp1<<<NB / MR, 256, 0, stream>>>(g_hist, st, st + 128, bn_g, bn_b,
                                        in_w, in_b, h1, st + 256, st + 384);
    k_final<<<NB / MR, 256, 0, stream>>>(h1, st + 256, st + 384, bn1_g, bn1_b,
                                         out_w, out_b, gate_w, gate_b,
                                         nodes, u2e, out);
}

// Round 5
// 558.966 us; speedup vs baseline: 2.8697x; 1.1278x over previous
//
#include <hip/hip_runtime.h>
#include <stdint.h>

#define NB 4096      // batch
#define NK 64        // neighbors
#define ND 128       // dim
#define NH 4         // heads
#define ES 136       // bf16 LDS row stride (ushorts): 272B, 16B-aligned rows
#define ESW (ES/2)   // 68 dwords per row
#define FS 130       // f32 stride for small kernels
#define MR 8         // row tile for mlp/final kernels

typedef __attribute__((ext_vector_type(8))) short bf16x8;
typedef __attribute__((ext_vector_type(4))) float f32x4;

// native selu: v_exp_f32-based (~5 VALU ops)
__device__ __forceinline__ float seluf(float x) {
    float e = 1.6732632423543772f * (__expf(x) - 1.f);
    return 1.0507009873554805f * (x > 0.f ? x : e);
}
__device__ __forceinline__ float sigmoidf_(float x) {
    return __fdividef(1.f, 1.f + __expf(-x));
}
__device__ __forceinline__ uint32_t f2bf2(float a, float b) {
    uint32_t ua = __float_as_uint(a); ua += 0x7fffu + ((ua >> 16) & 1u);
    uint32_t ub = __float_as_uint(b); ub += 0x7fffu + ((ub >> 16) & 1u);
    return (ua >> 16) | (ub & 0xffff0000u);
}
__device__ __forceinline__ uint16_t bf1(float v) {
    uint32_t u = __float_as_uint(v); u += 0x7fffu + ((u >> 16) & 1u);
    return (uint16_t)(u >> 16);
}
__device__ __forceinline__ float bflo(uint32_t v) { return __uint_as_float(v << 16); }
__device__ __forceinline__ float bfhi(uint32_t v) { return __uint_as_float(v & 0xffff0000u); }
__device__ __forceinline__ float bf2f(uint16_t h) { return __uint_as_float(((uint32_t)h) << 16); }

// ------------------------------------------------- prep: transpose weights to bf16 K-major
// wt1[h][n][k] = att1_w[h][k][n]  (k<128, n<128)   wt2[h][c][d] = att2_w[h][d][c]
// 16 blocks: h = bx>>2, quarter q = bx&3
__global__ __launch_bounds__(256)
void k_prep(const float* __restrict__ att1_w, const float* __restrict__ att2_w,
            uint16_t* __restrict__ wt1, uint16_t* __restrict__ wt2)
{
    const int h = blockIdx.x >> 2;
    const int q = blockIdx.x & 3;
    const int t = threadIdx.x;
    {
        int n = t >> 1, kh = t & 1;
        for (int k0 = q * 16; k0 < q * 16 + 16; ++k0) {
            int k = k0 * 2 + kh;
            float v = att1_w[(size_t)h * 32768 + (size_t)k * ND + n];
            float vo = __shfl_xor(v, 1, 64);
            if (kh == 0)
                ((uint32_t*)wt1)[((size_t)h * ND + n) * 64 + k0] = f2bf2(v, vo);
        }
    }
    {
        int c = t & 31, dh = t >> 5;
        for (int d0 = q * 4; d0 < q * 4 + 4; ++d0) {
            int d = d0 * 8 + dh;
            float v = att2_w[(size_t)h * 4096 + (size_t)d * 32 + c];
            float vo = __shfl_xor(v, 32, 64);
            if ((dh & 1) == 0)
                ((uint32_t*)wt2)[((size_t)h * 32 + c) * 64 + d0 * 4 + (dh >> 1)] = f2bf2(v, vo);
        }
    }
}

// ---------------------------------------------------------------- kernel 1
__global__ __launch_bounds__(256, 4)
void k_att(const int* __restrict__ nodes, const int* __restrict__ neighbors,
           const float* __restrict__ u2e,
           const float* __restrict__ att1_w, const float* __restrict__ att1_b,
           const float* __restrict__ att2_b,
           const float* __restrict__ att3_w, const float* __restrict__ att3_b,
           const float* __restrict__ lin1_w, const float* __restrict__ lin1_b,
           const uint16_t* __restrict__ wt1, const uint16_t* __restrict__ wt2,
           float* __restrict__ hist_out,
           float* __restrict__ sums, float* __restrict__ sumsq)
{
    __shared__ alignas(16) uint16_t e_sh[NK * ES];   // normalized neighbor embeds, bf16
    __shared__ alignas(16) uint16_t s1_sh[NK * ES];  // att1 output, bf16
    __shared__ float u_sh[ND], un_sh[ND], up_sh[ND], lw_sh[ND], hist_sh[ND];
    __shared__ float alpha_sh[NK], sc_sh[NK], att_sh[NK];
    __shared__ float red_sh[512];
    __shared__ float rnorm_sh;

    const int b = blockIdx.x;
    const int t = threadIdx.x;
    const int lane = t & 63;
    const int wave = t >> 6;
    const int lh = lane & 15;   // fragment col / row-in-tile
    const int lg = lane >> 4;   // k-group

    // ---- gather neighbors + l2norm into LDS (bf16) ----
    for (int k = wave; k < NK; k += 4) {
        int idx = neighbors[b * NK + k];
        float2 v = ((const float2*)(u2e + (size_t)idx * ND))[lane];
        float ss = v.x * v.x + v.y * v.y;
        #pragma unroll
        for (int m = 1; m < 64; m <<= 1) ss += __shfl_xor(ss, m, 64);
        float r = 1.0f / fmaxf(sqrtf(ss), 1e-12f);
        ((uint32_t*)e_sh)[k * ESW + lane] = f2bf2(v.x * r, v.y * r);
    }
    if (t < ND) {
        u_sh[t] = u2e[(size_t)nodes[b] * ND + t];
        hist_sh[t] = 0.f;
    }
    __syncthreads();

    for (int h = 0; h < NH; ++h) {
        // ---- u_n = l2norm(u) ----
        if (wave == 0) {
            float a = u_sh[lane], c = u_sh[lane + 64];
            float ss = a * a + c * c;
            #pragma unroll
            for (int m = 1; m < 64; m <<= 1) ss += __shfl_xor(ss, m, 64);
            if (lane == 0) rnorm_sh = 1.0f / fmaxf(sqrtf(ss), 1e-12f);
        }
        __syncthreads();
        if (t < ND) {
            un_sh[t] = u_sh[t] * rnorm_sh;
            lw_sh[t] = lin1_w[h * ND + t];
        }
        __syncthreads();

        // ---- uproj partials (rank-1 half of att1, VALU) ----
        {
            int d = t & 127, half = t >> 7;
            const float* wb = att1_w + (size_t)h * 32768 + (size_t)(ND + half * 64) * ND + d;
            float p = 0.f;
            #pragma unroll 8
            for (int j = 0; j < 64; ++j)
                p += un_sh[half * 64 + j] * wb[j * ND];
            red_sh[t] = p;
        }
        // ---- alpha = sigmoid(e_n . lin1_w + b) + 1 ----
        {
            int k = t >> 2, qd = t & 3;
            const uint32_t* er = (const uint32_t*)e_sh + k * ESW + qd * 16;
            const float* lr = lw_sh + qd * 32;
            float ap = 0.f;
            #pragma unroll 8
            for (int j2 = 0; j2 < 16; ++j2) {
                uint32_t v = er[j2];
                ap += bflo(v) * lr[2 * j2] + bfhi(v) * lr[2 * j2 + 1];
            }
            ap += __shfl_xor(ap, 1, 64);
            ap += __shfl_xor(ap, 2, 64);
            if (qd == 0)
                alpha_sh[k] = sigmoidf_(ap + lin1_b[h]) + 1.0f;
        }
        __syncthreads();
        if (t < ND)
            up_sh[t] = red_sh[t] + red_sh[t + 128] + att1_b[h * ND + t];
        __syncthreads();

        // ---- att1 via MFMA: C[64k][128n] = E[64,128] @ W1a[128,128] ----
        // wave w owns n in [w*32, w*32+32)
        {
            const uint16_t* WB = wt1 + ((size_t)h * ND + wave * 32) * ND;
            bf16x8 B[4][2];
            #pragma unroll
            for (int kk = 0; kk < 4; ++kk)
                #pragma unroll
                for (int nt = 0; nt < 2; ++nt)
                    B[kk][nt] = *(const bf16x8*)(WB + (nt * 16 + lh) * ND + kk * 32 + lg * 8);
            f32x4 z = {0.f, 0.f, 0.f, 0.f};
            f32x4 acc[4][2] = {{z, z}, {z, z}, {z, z}, {z, z}};
            #pragma unroll
            for (int mt = 0; mt < 4; ++mt) {
                #pragma unroll
                for (int kk = 0; kk < 4; ++kk) {
                    bf16x8 A = *(const bf16x8*)(e_sh + (mt * 16 + lh) * ES + kk * 32 + lg * 8);
                    acc[mt][0] = __builtin_amdgcn_mfma_f32_16x16x32_bf16(A, B[kk][0], acc[mt][0], 0, 0, 0);
                    acc[mt][1] = __builtin_amdgcn_mfma_f32_16x16x32_bf16(A, B[kk][1], acc[mt][1], 0, 0, 0);
                }
            }
            float up0 = up_sh[wave * 32 + lh];
            float up1 = up_sh[wave * 32 + 16 + lh];
            #pragma unroll
            for (int mt = 0; mt < 4; ++mt)
                #pragma unroll
                for (int nt = 0; nt < 2; ++nt) {
                    float upv = nt ? up1 : up0;
                    #pragma unroll
                    for (int r = 0; r < 4; ++r) {
                        float v = seluf(acc[mt][nt][r] + upv);
                        s1_sh[(mt * 16 + lg * 4 + r) * ES + wave * 32 + nt * 16 + lh] = bf1(v);
                    }
                }
        }
        __syncthreads();

        // ---- att2 via MFMA: C2[64k][32c] = S1[64,128] @ W2[128,32]; then selu+att3 dot ----
        // wave w owns rows [w*16, w*16+16)
        {
            const uint16_t* WB2 = wt2 + (size_t)h * 32 * ND;
            bf16x8 B2[4][2];
            #pragma unroll
            for (int kk = 0; kk < 4; ++kk)
                #pragma unroll
                for (int nt = 0; nt < 2; ++nt)
                    B2[kk][nt] = *(const bf16x8*)(WB2 + (nt * 16 + lh) * ND + kk * 32 + lg * 8);
            f32x4 z = {0.f, 0.f, 0.f, 0.f};
            f32x4 acc2[2] = {z, z};
            #pragma unroll
            for (int kk = 0; kk < 4; ++kk) {
                bf16x8 A = *(const bf16x8*)(s1_sh + (wave * 16 + lh) * ES + kk * 32 + lg * 8);
                acc2[0] = __builtin_amdgcn_mfma_f32_16x16x32_bf16(A, B2[kk][0], acc2[0], 0, 0, 0);
                acc2[1] = __builtin_amdgcn_mfma_f32_16x16x32_bf16(A, B2[kk][1], acc2[1], 0, 0, 0);
            }
            float w3a = att3_w[h * 32 + lh],      b2a = att2_b[h * 32 + lh];
            float w3b = att3_w[h * 32 + 16 + lh], b2b = att2_b[h * 32 + 16 + lh];
            float b3 = att3_b[h];
            #pragma unroll
            for (int r = 0; r < 4; ++r) {
                float v = seluf(acc2[0][r] + b2a) * w3a + seluf(acc2[1][r] + b2b) * w3b;
                v += __shfl_xor(v, 1, 64);
                v += __shfl_xor(v, 2, 64);
                v += __shfl_xor(v, 4, 64);
                v += __shfl_xor(v, 8, 64);
                if (lh == 0)
                    sc_sh[wave * 16 + lg * 4 + r] = v + b3;
            }
        }
        __syncthreads();

        // ---- entmax: Newton on f(tau)=sum max(xs-tau,0)^q - 1 (convex, from f>=0 side) ----
        if (wave == 0) {
            float x   = sc_sh[lane];
            float am1 = alpha_sh[lane] - 1.0f;
            float q   = 1.0f / am1;
            float em1 = q - 1.0f;
            float xs  = x * am1;
            float mx = xs;
            #pragma unroll
            for (int m = 1; m < 64; m <<= 1) mx = fmaxf(mx, __shfl_xor(mx, m, 64));
            float tau = mx - 1.0f;
            for (int it = 0; it < 8; ++it) {
                float tt = xs - tau;
                bool pos = tt > 0.f;
                float lgn = __logf(pos ? tt : 1.f);
                float p  = pos ? __expf(q * lgn) : 0.f;
                float dp = pos ? q * __expf(em1 * lgn) : 0.f;
                float s0 = p, s1 = dp;
                #pragma unroll
                for (int m = 1; m < 64; m <<= 1) {
                    s0 += __shfl_xor(s0, m, 64);
                    s1 += __shfl_xor(s1, m, 64);
                }
                tau += __fdividef(s0 - 1.0f, fmaxf(s1, 1e-30f));
                tau = fminf(tau, mx - 1e-6f);
            }
            float tt = xs - tau;
            bool pos = tt > 0.f;
            float p = pos ? __expf(q * __logf(pos ? tt : 1.f)) : 0.f;
            float s0 = p;
            #pragma unroll
            for (int m = 1; m < 64; m <<= 1) s0 += __shfl_xor(s0, m, 64);
            att_sh[lane] = __fdividef(p, s0);
        }
        __syncthreads();

        // ---- pool: u[d] = sum_k e_n[k][d] * att[k]; hist += u (dword-wise) ----
        {
            int d2 = t & 63, qk = t >> 6;
            const uint32_t* E = (const uint32_t*)e_sh;
            float px = 0.f, py = 0.f;
            #pragma unroll 8
            for (int k = qk * 16; k < qk * 16 + 16; ++k) {
                uint32_t v = E[k * ESW + d2];
                float a = att_sh[k];
                px += bflo(v) * a;
                py += bfhi(v) * a;
            }
            red_sh[qk * 128 + d2 * 2]     = px;
            red_sh[qk * 128 + d2 * 2 + 1] = py;
        }
        __syncthreads();
        if (t < ND) {
            float un = red_sh[t] + red_sh[128 + t] + red_sh[256 + t] + red_sh[384 + t];
            u_sh[t] = un;
            hist_sh[t] += un;
        }
        __syncthreads();
    }
    if (t < ND) {
        float hv = hist_sh[t] * 0.25f;
        hist_out[(size_t)b * ND + t] = hv;
        atomicAdd(&sums[t], hv);
        atomicAdd(&sumsq[t], hv * hv);
    }
}

// ---------------------------------------------------------------- h1 = selu(bn(hist) @ in_w + in_b), fused h1 stats
// grid NB/MR = 512, 4 cols/thread
__global__ __launch_bounds__(256)
void k_mlp1(const float* __restrict__ hist,
            const float* __restrict__ sums, const float* __restrict__ sumsq,
            const float* __restrict__ bn_g, const float* __restrict__ bn_b,
            const float* __restrict__ in_w, const float* __restrict__ in_b,
            float* __restrict__ h1out,
            float* __restrict__ sums1, float* __restrict__ sumsq1)
{
    __shared__ float xh[MR * FS];
    int t = threadIdx.x;
    int row0 = blockIdx.x * MR;
    for (int i = t; i < MR * ND; i += 256) {
        int r = i >> 7, d = i & 127;
        float m  = sums[d]  * (1.f / 4096.f);
        float vv = sumsq[d] * (1.f / 4096.f) - m * m;
        float sc = bn_g[d] * rsqrtf(vv + 1e-5f);
        float sh = bn_b[d] - m * sc;
        xh[r * FS + d] = hist[(size_t)(row0 + r) * ND + d] * sc + sh;
    }
    __syncthreads();
    int dg = t & 31, rg = t >> 5;
    int d0 = dg * 4;
    float acc[4] = {};
    for (int j = 0; j < ND; ++j) {
        float4 wa = *(const float4*)(in_w + (size_t)j * ND + d0);
        float e = xh[rg * FS + j];
        acc[0] += e * wa.x; acc[1] += e * wa.y;
        acc[2] += e * wa.z; acc[3] += e * wa.w;
    }
    float hv[4];
    #pragma unroll
    for (int c = 0; c < 4; ++c) {
        hv[c] = seluf(acc[c] + in_b[d0 + c]);
        h1out[(size_t)(row0 + rg) * ND + d0 + c] = hv[c];
    }
    __syncthreads();
    #pragma unroll
    for (int c = 0; c < 4; ++c) xh[rg * FS + d0 + c] = hv[c];
    __syncthreads();
    if (t < ND) {
        float s = 0.f, q = 0.f;
        #pragma unroll
        for (int r = 0; r < MR; ++r) {
            float v = xh[r * FS + t];
            s += v; q += v * v;
        }
        atomicAdd(&sums1[t], s);
        atomicAdd(&sumsq1[t], q);
    }
}

// ---------------------------------------------------------------- final: neigh = bn1(h1)@out_w+b; gated combine
// grid NB/MR = 512, 4 cols/thread
__global__ __launch_bounds__(256)
void k_final(const float* __restrict__ h1,
             const float* __restrict__ sums1, const float* __restrict__ sumsq1,
             const float* __restrict__ bn1_g, const float* __restrict__ bn1_b,
             const float* __restrict__ out_w, const float* __restrict__ out_b,
             const float* __restrict__ gate_w, const float* __restrict__ gate_b,
             const int* __restrict__ nodes, const float* __restrict__ u2e,
             float* __restrict__ out)
{
    __shared__ float xh[MR * FS];
    __shared__ float sf[MR * FS];
    __shared__ float ng[MR * FS];
    int t = threadIdx.x;
    int row0 = blockIdx.x * MR;
    for (int i = t; i < MR * ND; i += 256) {
        int r = i >> 7, d = i & 127;
        float m  = sums1[d]  * (1.f / 4096.f);
        float vv = sumsq1[d] * (1.f / 4096.f) - m * m;
        float sc = bn1_g[d] * rsqrtf(vv + 1e-5f);
        float sh = bn1_b[d] - m * sc;
        xh[r * FS + d] = h1[(size_t)(row0 + r) * ND + d] * sc + sh;
        sf[r * FS + d] = u2e[(size_t)nodes[row0 + r] * ND + d];
    }
    __syncthreads();
    int dg = t & 31, rg = t >> 5;
    int d0 = dg * 4;
    {
        float acc[4] = {};
        for (int j = 0; j < ND; ++j) {
            float4 wa = *(const float4*)(out_w + (size_t)j * ND + d0);
            float e = xh[rg * FS + j];
            acc[0] += e * wa.x; acc[1] += e * wa.y;
            acc[2] += e * wa.z; acc[3] += e * wa.w;
        }
        #pragma unroll
        for (int c = 0; c < 4; ++c)
            ng[rg * FS + d0 + c] = acc[c] + out_b[d0 + c];
    }
    __syncthreads();
    {
        float acc[4] = {};
        for (int j = 0; j < ND; ++j) {
            float4 w0 = *(const float4*)(gate_w + (size_t)j * ND + d0);
            float4 w1 = *(const float4*)(gate_w + (size_t)(ND + j) * ND + d0);
            float4 w2 = *(const float4*)(gate_w + (size_t)(2 * ND + j) * ND + d0);
            float s = sf[rg * FS + j];
            float n = ng[rg * FS + j];
            float p = s * n;
            acc[0] += s * w0.x + n * w1.x + p * w2.x;
            acc[1] += s * w0.y + n * w1.y + p * w2.y;
            acc[2] += s * w0.z + n * w1.z + p * w2.z;
            acc[3] += s * w0.w + n * w1.w + p * w2.w;
        }
        #pragma unroll
        for (int c = 0; c < 4; ++c) {
            int d = d0 + c;
            float gama = sigmoidf_(acc[c] + gate_b[d]);
            float s = sf[rg * FS + d];
            float n = ng[rg * FS + d];
            out[(size_t)(row0 + rg) * ND + d] = gama * s + (1.f - gama) * n;
        }
    }
}

// ---------------------------------------------------------------- launch
extern "C" void kernel_launch(void* const* d_in, const int* in_sizes, int n_in,
                              void* d_out, int out_size, void* d_ws, size_t ws_size,
                              hipStream_t stream)
{
    const int*   nodes     = (const int*)d_in[0];
    const int*   neighbors = (const int*)d_in[1];
    const float* u2e       = (const float*)d_in[2];
    const float* att1_w    = (const float*)d_in[3];
    const float* att1_b    = (const float*)d_in[4];
    const float* att2_w    = (const float*)d_in[5];
    const float* att2_b    = (const float*)d_in[6];
    const float* att3_w    = (const float*)d_in[7];
    const float* att3_b    = (const float*)d_in[8];
    const float* lin1_w    = (const float*)d_in[9];
    const float* lin1_b    = (const float*)d_in[10];
    const float* gate_w    = (const float*)d_in[11];
    const float* gate_b    = (const float*)d_in[12];
    const float* bn_g      = (const float*)d_in[13];
    const float* bn_b      = (const float*)d_in[14];
    const float* bn1_g     = (const float*)d_in[15];
    const float* bn1_b     = (const float*)d_in[16];
    const float* in_w      = (const float*)d_in[17];
    const float* in_b      = (const float*)d_in[18];
    const float* out_w     = (const float*)d_in[19];
    const float* out_b     = (const float*)d_in[20];
    float* out = (float*)d_out;

    float* ws     = (float*)d_ws;
    float* g_hist = ws;                             // 4096*128 f32
    float* h1     = ws + (size_t)NB * ND;           // 4096*128 f32
    float* st     = ws + (size_t)2 * NB * ND;       // 512 f32 stats
    uint16_t* wt1 = (uint16_t*)(ws + (size_t)2 * NB * ND + 512);  // 4*128*128 bf16
    uint16_t* wt2 = wt1 + (size_t)NH * ND * ND;                   // 4*32*128 bf16

    (void)hipMemsetAsync(st, 0, 512 * sizeof(float), stream);

    k_prep<<<16, 256, 0, stream>>>(att1_w, att2_w, wt1, wt2);
    k_att<<<NB, 256, 0, stream>>>(nodes, neighbors, u2e,
                                  att1_w, att1_b, att2_b,
                                  att3_w, att3_b, lin1_w, lin1_b,
                                  wt1, wt2,
                                  g_hist, st, st + 128);
    k_mlp1<<<NB / MR, 256, 0, stream>>>(g_hist, st, st + 128, bn_g, bn_b,
                                        in_w, in_b, h1, st + 256, st + 384);
    k_final<<<NB / MR, 256, 0, stream>>>(h1, st + 256, st + 384, bn1_g, bn1_b,
                                         out_w, out_b, gate_w, gate_b,
                                         nodes, u2e, out);
}